// Round 2
// baseline (195.698 us; speedup 1.0000x reference)
//
#include <hip/hip_runtime.h>
#include <math.h>

#define PBLOCK 256
#define MT 1024          // main kernel threads: 16 waves
#define NW 16            // waves per block
#define IPG 256          // i's per group (4 per lane)
#define NSPLIT 8         // j-splits per group
#define BLOCK 256        // fallback block size

// K1: pack (T, exp(theta)); zero tickets + accum (replaces any memset).
__global__ void surv_prep(const float* __restrict__ theta,
                          const float* __restrict__ T,
                          float2* __restrict__ PE,
                          int* __restrict__ ticket_g, int* __restrict__ ticket_global,
                          float* __restrict__ accum, int n, int ng) {
    int i = blockIdx.x * PBLOCK + threadIdx.x;
    if (i < n) PE[i] = make_float2(T[i], expf(theta[i]));
    if (i < ng) ticket_g[i] = 0;
    if (i == 0) { *ticket_global = 0; *accum = 0.f; }
}

// K2: O(n^2) sweep, 4 i's per lane (24 VALU ops per 16B load), 8-way j-split,
// coherent-point partial exchange + ticketed in-kernel finalize.
__global__ __launch_bounds__(MT, 8) void surv_main(
        const float* __restrict__ theta, const float* __restrict__ T,
        const float* __restrict__ events, const float2* __restrict__ PE,
        float* __restrict__ partial, int* __restrict__ ticket_g,
        int* __restrict__ ticket_global, float* __restrict__ accum,
        float* __restrict__ out, int n, int ng) {
    __shared__ float part[NW][IPG];   // 16 KB
    __shared__ float wsum[NW];
    __shared__ int flag;

    const int tid  = threadIdx.x;
    const int w    = tid >> 6;
    const int lane = tid & 63;
    const int g    = blockIdx.x >> 3;        // i-group       (0..ng-1)
    const int s    = blockIdx.x & (NSPLIT-1);// j-split       (0..7)
    const int ibase = g * IPG;

    // 4 i's per lane, coalesced loads
    const float Ti0 = T[ibase + lane];
    const float Ti1 = T[ibase + 64  + lane];
    const float Ti2 = T[ibase + 128 + lane];
    const float Ti3 = T[ibase + 192 + lane];

    const int jcount = n / NSPLIT;           // j's per block (2048 @ n=16K)
    const int jw     = jcount / NW;          // j's per wave  (128)
    const int nq     = jw >> 1;              // float4 loads  (64)
    const float4* __restrict__ PE4 = (const float4*)PE;
    const int q0 = (s * jcount + w * jw) >> 1;   // wave-uniform start

    float a0=0.f,a1=0.f,a2=0.f,a3=0.f;       // pair-slot x
    float b0=0.f,b1=0.f,b2=0.f,b3=0.f;       // pair-slot z
    #pragma unroll 4
    for (int q = 0; q < nq; ++q) {
        float4 v = PE4[q0 + q];              // broadcast, L2-resident
        a0 += (v.x >= Ti0) ? v.y : 0.f;
        a1 += (v.x >= Ti1) ? v.y : 0.f;
        a2 += (v.x >= Ti2) ? v.y : 0.f;
        a3 += (v.x >= Ti3) ? v.y : 0.f;
        b0 += (v.z >= Ti0) ? v.w : 0.f;
        b1 += (v.z >= Ti1) ? v.w : 0.f;
        b2 += (v.z >= Ti2) ? v.w : 0.f;
        b3 += (v.z >= Ti3) ? v.w : 0.f;
    }
    part[w][lane]        = a0 + b0;
    part[w][64  + lane]  = a1 + b1;
    part[w][128 + lane]  = a2 + b2;
    part[w][192 + lane]  = a3 + b3;
    __syncthreads();

    // cross-wave reduce; publish this split's 256 partials at the coherent point
    if (tid < IPG) {
        float v = 0.f;
        #pragma unroll
        for (int ww = 0; ww < NW; ++ww) v += part[ww][tid];
        atomicExch(&partial[(s * ng + g) * IPG + tid], v);  // single writer/slot
    }
    __threadfence();
    __syncthreads();
    if (tid == 0) {
        int t = atomicAdd(&ticket_g[g], 1);
        flag = (t == NSPLIT - 1) ? 1 : 0;
    }
    __syncthreads();

    if (flag) {   // last split of this group: finalize the 256 terms
        float term = 0.f;
        if (tid < IPG) {
            const int i = ibase + tid;
            float r = 0.f;
            #pragma unroll
            for (int ss = 0; ss < NSPLIT; ++ss)   // 8 independent RMW reads (coherent)
                r += atomicAdd(&partial[(ss * ng + g) * IPG + tid], 0.f);
            term = (theta[i] - logf(r)) * events[i];
        }
        #pragma unroll
        for (int off = 32; off > 0; off >>= 1)
            term += __shfl_down(term, off, 64);
        if (lane == 0) wsum[w] = term;           // waves 4..15 write 0
        __syncthreads();
        if (tid == 0) {
            float gs = wsum[0] + wsum[1] + wsum[2] + wsum[3];
            atomicAdd(accum, gs);
            __threadfence();
            int t2 = atomicAdd(ticket_global, 1);
            if (t2 == ng - 1) {
                float tot = atomicAdd(accum, 0.f);  // RMW read at coherent point
                out[0] = -tot / (float)n;
            }
        }
    }
}

// ---------- brute-force fallback (generic n) ----------
__global__ void surv_partial_bf(const float* __restrict__ theta, const float* __restrict__ T,
                                const float* __restrict__ events, float* __restrict__ bsum, int n) {
    __shared__ float red[BLOCK];
    const int tid = threadIdx.x;
    const int i = blockIdx.x * BLOCK + tid;
    float term = 0.f;
    if (i < n) {
        const float Ti = T[i];
        float risk = 0.f;
        for (int j = 0; j < n; ++j)
            risk += (T[j] >= Ti) ? expf(theta[j]) : 0.f;
        term = (theta[i] - logf(risk)) * events[i];
    }
    red[tid] = term;
    __syncthreads();
    for (int s = BLOCK / 2; s > 0; s >>= 1) {
        if (tid < s) red[tid] += red[tid + s];
        __syncthreads();
    }
    if (tid == 0) bsum[blockIdx.x] = red[0];
}

__global__ void surv_final(const float* __restrict__ bsum, float* __restrict__ out,
                           int nblocks, int n) {
    float v = 0.f;
    for (int b = threadIdx.x; b < nblocks; b += 64) v += bsum[b];
    for (int off = 32; off > 0; off >>= 1) v += __shfl_down(v, off, 64);
    if (threadIdx.x == 0) out[0] = -v / (float)n;
}

extern "C" void kernel_launch(void* const* d_in, const int* in_sizes, int n_in,
                              void* d_out, int out_size, void* d_ws, size_t ws_size,
                              hipStream_t stream) {
    const float* theta  = (const float*)d_in[0];
    const float* T      = (const float*)d_in[1];
    const float* events = (const float*)d_in[2];
    float* out = (float*)d_out;
    const int n = in_sizes[0];                  // 16384

    // fast path: n divisible by 2048 (groups of 256 i, 8 j-splits, 16 waves, float4-even)
    // ws: PE[n] float2 | partial[NSPLIT * (n/IPG) * IPG] f32 | ticket_g[ng] | ticket_global | accum
    const int ng = n / IPG;
    const size_t need = (size_t)n * 8 + (size_t)NSPLIT * n * 4 + (size_t)(ng + 2) * 4 + 64;
    const bool fast = (n >= 2048) && (n % 2048 == 0) && ((size_t)ws_size >= need);

    if (!fast) {
        const int nbi = (n + BLOCK - 1) / BLOCK;
        float* bsum = (float*)d_ws;
        surv_partial_bf<<<nbi, BLOCK, 0, stream>>>(theta, T, events, bsum, n);
        surv_final<<<1, 64, 0, stream>>>(bsum, out, nbi, n);
        return;
    }

    float2* PE       = (float2*)d_ws;
    float*  partial  = (float*)(PE + n);
    int*    ticket_g = (int*)(partial + (size_t)NSPLIT * n);
    int*    ticket_global = ticket_g + ng;
    float*  accum    = (float*)(ticket_global + 1);

    const int pb = (n + PBLOCK - 1) / PBLOCK;
    const int mb = ng * NSPLIT;                 // 512 blocks @ n=16K

    surv_prep<<<pb, PBLOCK, 0, stream>>>(theta, T, PE, ticket_g, ticket_global, accum, n, ng);
    surv_main<<<mb, MT, 0, stream>>>(theta, T, events, PE, partial, ticket_g,
                                     ticket_global, accum, out, n, ng);
}

// Round 3
// 79.824 us; speedup vs baseline: 2.4516x; 2.4516x over previous
//
#include <hip/hip_runtime.h>
#include <math.h>

#define MT 1024          // main kernel threads: 16 waves
#define NW 16            // waves per block
#define IPG 256          // i's per group (4 per lane)
#define NSPLIT 8         // j-splits per group
#define MAXJ 2048        // max j's staged in LDS per block (16 KB)
#define FBLOCK 256       // finalize block size
#define BLOCK 256        // fallback block size

// K1: O(n^2) sweep. Block (g,s): i-group g (256 i's, 4/lane), j-split s.
//  - stage j-slice (T_j, exp(theta_j)) into LDS (expf computed here: no prep
//    kernel, no PE array).
//  - 16 waves each sweep 1/16 of the slice with wave-uniform ds_read_b128
//    (broadcast, ~120 cyc latency vs ~400 for L2) -> 24 VALU ops per 16 B.
//  - cross-wave LDS reduce; PLAIN stores of 256 partials. No atomics, no
//    fences: the dispatch boundary makes stores visible to K2 (R2's in-kernel
//    atomic fabric was the 144 us regression).
__global__ __launch_bounds__(MT, 8) void surv_main(
        const float* __restrict__ theta, const float* __restrict__ T,
        float* __restrict__ partial, float* __restrict__ accum,
        int* __restrict__ ticket, int n) {
    __shared__ float2 sPE[MAXJ];      // 16 KB staged (T, E) pairs
    __shared__ float part[NW][IPG];   // 16 KB cross-wave partials

    const int tid  = threadIdx.x;
    const int w    = tid >> 6;
    const int lane = tid & 63;
    const int g    = blockIdx.x >> 3;         // i-group
    const int s    = blockIdx.x & (NSPLIT-1); // j-split
    const int ibase = g * IPG;

    if (blockIdx.x == 0 && tid == 0) { *accum = 0.f; *ticket = 0; }

    // stage this block's j-slice
    const int jcount = n / NSPLIT;            // 2048 @ n=16K
    const int j0 = s * jcount;
    for (int j = tid; j < jcount; j += MT)
        sPE[j] = make_float2(T[j0 + j], expf(theta[j0 + j]));

    // 4 i's per lane, coalesced
    const float Ti0 = T[ibase + lane];
    const float Ti1 = T[ibase + 64  + lane];
    const float Ti2 = T[ibase + 128 + lane];
    const float Ti3 = T[ibase + 192 + lane];
    __syncthreads();

    const int jw = jcount / NW;               // j's per wave (128)
    const int nq = jw >> 1;                   // float4 (2-pair) reads (64)
    const float4* sPE4 = (const float4*)sPE;
    const int qb = (w * jw) >> 1;             // wave-uniform LDS base

    float a0=0.f,a1=0.f,a2=0.f,a3=0.f;        // pair slot (x,y)
    float b0=0.f,b1=0.f,b2=0.f,b3=0.f;        // pair slot (z,w)
    #pragma unroll 8
    for (int q = 0; q < nq; ++q) {
        float4 v = sPE4[qb + q];              // broadcast ds_read_b128
        a0 += (v.x >= Ti0) ? v.y : 0.f;
        a1 += (v.x >= Ti1) ? v.y : 0.f;
        a2 += (v.x >= Ti2) ? v.y : 0.f;
        a3 += (v.x >= Ti3) ? v.y : 0.f;
        b0 += (v.z >= Ti0) ? v.w : 0.f;
        b1 += (v.z >= Ti1) ? v.w : 0.f;
        b2 += (v.z >= Ti2) ? v.w : 0.f;
        b3 += (v.z >= Ti3) ? v.w : 0.f;
    }
    part[w][lane]       = a0 + b0;
    part[w][64  + lane] = a1 + b1;
    part[w][128 + lane] = a2 + b2;
    part[w][192 + lane] = a3 + b3;
    __syncthreads();

    if (tid < IPG) {
        float v = 0.f;
        #pragma unroll
        for (int ww = 0; ww < NW; ++ww) v += part[ww][tid];
        partial[(size_t)s * n + ibase + tid] = v;   // plain store
    }
}

// K2: finalize. i = global index; sum the 8 split-partials (visible via the
// dispatch boundary), compute the log-term, reduce; tiny atomic+ticket scale
// (64 blocks) proven cheap in R1.
__global__ __launch_bounds__(FBLOCK) void surv_fin(
        const float* __restrict__ theta, const float* __restrict__ events,
        const float* __restrict__ partial, float* __restrict__ accum,
        int* __restrict__ ticket, float* __restrict__ out, int n) {
    __shared__ float red[FBLOCK];
    const int tid = threadIdx.x;
    const int i = blockIdx.x * FBLOCK + tid;
    float r = 0.f;
    #pragma unroll
    for (int s = 0; s < NSPLIT; ++s) r += partial[(size_t)s * n + i];
    red[tid] = (theta[i] - logf(r)) * events[i];
    __syncthreads();
    for (int s = FBLOCK / 2; s > 0; s >>= 1) {
        if (tid < s) red[tid] += red[tid + s];
        __syncthreads();
    }
    if (tid == 0) {
        atomicAdd(accum, red[0]);
        __threadfence();
        int t = atomicAdd(ticket, 1);
        if (t == (int)gridDim.x - 1) {
            float tot = atomicAdd(accum, 0.f);   // RMW read at coherent point
            out[0] = -tot / (float)n;
        }
    }
}

// ---------- brute-force fallback (generic n) ----------
__global__ void surv_partial_bf(const float* __restrict__ theta, const float* __restrict__ T,
                                const float* __restrict__ events, float* __restrict__ bsum, int n) {
    __shared__ float red[BLOCK];
    const int tid = threadIdx.x;
    const int i = blockIdx.x * BLOCK + tid;
    float term = 0.f;
    if (i < n) {
        const float Ti = T[i];
        float risk = 0.f;
        for (int j = 0; j < n; ++j)
            risk += (T[j] >= Ti) ? expf(theta[j]) : 0.f;
        term = (theta[i] - logf(risk)) * events[i];
    }
    red[tid] = term;
    __syncthreads();
    for (int s = BLOCK / 2; s > 0; s >>= 1) {
        if (tid < s) red[tid] += red[tid + s];
        __syncthreads();
    }
    if (tid == 0) bsum[blockIdx.x] = red[0];
}

__global__ void surv_final(const float* __restrict__ bsum, float* __restrict__ out,
                           int nblocks, int n) {
    float v = 0.f;
    for (int b = threadIdx.x; b < nblocks; b += 64) v += bsum[b];
    for (int off = 32; off > 0; off >>= 1) v += __shfl_down(v, off, 64);
    if (threadIdx.x == 0) out[0] = -v / (float)n;
}

extern "C" void kernel_launch(void* const* d_in, const int* in_sizes, int n_in,
                              void* d_out, int out_size, void* d_ws, size_t ws_size,
                              hipStream_t stream) {
    const float* theta  = (const float*)d_in[0];
    const float* T      = (const float*)d_in[1];
    const float* events = (const float*)d_in[2];
    float* out = (float*)d_out;
    const int n = in_sizes[0];                  // 16384

    // fast path: n % 2048 == 0 (256-i groups, 8 splits, 16 waves, float4-even)
    // and j-slice fits the 16 KB LDS stage.
    // ws: partial[NSPLIT][n] f32 | accum | ticket
    const size_t need = (size_t)NSPLIT * n * 4 + 64;
    const bool fast = (n >= 2048) && (n % 2048 == 0) && (n / NSPLIT <= MAXJ)
                      && ((size_t)ws_size >= need);

    if (!fast) {
        const int nbi = (n + BLOCK - 1) / BLOCK;
        float* bsum = (float*)d_ws;
        surv_partial_bf<<<nbi, BLOCK, 0, stream>>>(theta, T, events, bsum, n);
        surv_final<<<1, 64, 0, stream>>>(bsum, out, nbi, n);
        return;
    }

    float* partial = (float*)d_ws;
    float* accum   = partial + (size_t)NSPLIT * n;
    int*   ticket  = (int*)(accum + 1);

    const int ng = n / IPG;                     // 64
    const int mb = ng * NSPLIT;                 // 512 blocks
    const int fb = n / FBLOCK;                  // 64 blocks

    surv_main<<<mb, MT, 0, stream>>>(theta, T, partial, accum, ticket, n);
    surv_fin<<<fb, FBLOCK, 0, stream>>>(theta, events, partial, accum, ticket, out, n);
}

// Round 4
// 79.260 us; speedup vs baseline: 2.4691x; 1.0071x over previous
//
#include <hip/hip_runtime.h>
#include <math.h>

#define MT 1024          // main kernel threads: 16 waves
#define NW 16            // waves per block
#define IPG 512          // i's per group (8 per lane): 48 VALU per ds_read_b128
#define NSPLIT 16        // j-splits per group (grid = (n/IPG)*NSPLIT)
#define MAXJ 2048        // max j's staged in LDS per block
#define FBLOCK 256       // finalize block size
#define BLOCK 256        // fallback block size

// K1: O(n^2) sweep. Block (g,s): i-group g (512 i's, 8/lane), j-split s.
//  R3 post-mortem: at IPG=256 the DS pipe (32 waves x 64 iters x ~12cyc) was
//  exactly co-saturated with the VALU (24.6K cyc each per CU/SIMD) -> poor
//  overlap ~26us. IPG=512 gives 48 VALU instrs per ds_read_b128: DS drops to
//  50% of VALU time and hides fully. VALU floor = n^2*3 lane-ops = 10.2us.
__global__ __launch_bounds__(MT, 8) void surv_main(
        const float* __restrict__ theta, const float* __restrict__ T,
        float* __restrict__ partial, float* __restrict__ accum,
        int* __restrict__ ticket, int n) {
    __shared__ float2 sPE[MAXJ];      // staged (T, E) pairs (8 KB used @ n=16K)
    __shared__ float part[NW][IPG];   // 32 KB cross-wave partials

    const int tid  = threadIdx.x;
    const int w    = tid >> 6;
    const int lane = tid & 63;
    const int g    = blockIdx.x >> 4;          // i-group
    const int s    = blockIdx.x & (NSPLIT-1);  // j-split
    const int ibase = g * IPG;

    if (blockIdx.x == 0 && tid == 0) { *accum = 0.f; *ticket = 0; }

    // stage this block's j-slice (1024 elems @ n=16K: one per thread)
    const int jcount = n / NSPLIT;
    const int j0 = s * jcount;
    for (int j = tid; j < jcount; j += MT)
        sPE[j] = make_float2(T[j0 + j], expf(theta[j0 + j]));

    // 8 i's per lane, coalesced
    float Ti[8];
    #pragma unroll
    for (int k = 0; k < 8; ++k) Ti[k] = T[ibase + k * 64 + lane];
    __syncthreads();

    const int jw = jcount / NW;                // j's per wave (64 @ n=16K)
    const int nq = jw >> 1;                    // float4 (2-pair) reads (32)
    const float4* sPE4 = (const float4*)sPE;
    const int qb = (w * jw) >> 1;              // wave-uniform LDS base

    float accA[8], accB[8];
    #pragma unroll
    for (int k = 0; k < 8; ++k) { accA[k] = 0.f; accB[k] = 0.f; }

    #pragma unroll 8
    for (int q = 0; q < nq; ++q) {
        float4 v = sPE4[qb + q];               // broadcast ds_read_b128
        #pragma unroll
        for (int k = 0; k < 8; ++k) {
            accA[k] += (v.x >= Ti[k]) ? v.y : 0.f;
            accB[k] += (v.z >= Ti[k]) ? v.w : 0.f;
        }
    }
    #pragma unroll
    for (int k = 0; k < 8; ++k)
        part[w][k * 64 + lane] = accA[k] + accB[k];
    __syncthreads();

    // cross-wave reduce; plain stores (dispatch boundary publishes to K2)
    for (int idx = tid; idx < IPG; idx += MT) {
        float v = 0.f;
        #pragma unroll
        for (int ww = 0; ww < NW; ++ww) v += part[ww][idx];
        partial[(size_t)s * n + ibase + idx] = v;
    }
}

// K2: finalize. Sum the 16 split-partials per i, log-term, reduce,
// tiny atomic+ticket in-kernel output (64 blocks - proven cheap).
__global__ __launch_bounds__(FBLOCK) void surv_fin(
        const float* __restrict__ theta, const float* __restrict__ events,
        const float* __restrict__ partial, float* __restrict__ accum,
        int* __restrict__ ticket, float* __restrict__ out, int n) {
    __shared__ float red[FBLOCK];
    const int tid = threadIdx.x;
    const int i = blockIdx.x * FBLOCK + tid;
    float r = 0.f;
    #pragma unroll
    for (int s = 0; s < NSPLIT; ++s) r += partial[(size_t)s * n + i];
    red[tid] = (theta[i] - logf(r)) * events[i];
    __syncthreads();
    for (int s = FBLOCK / 2; s > 0; s >>= 1) {
        if (tid < s) red[tid] += red[tid + s];
        __syncthreads();
    }
    if (tid == 0) {
        atomicAdd(accum, red[0]);
        __threadfence();
        int t = atomicAdd(ticket, 1);
        if (t == (int)gridDim.x - 1) {
            float tot = atomicAdd(accum, 0.f);   // RMW read at coherent point
            out[0] = -tot / (float)n;
        }
    }
}

// ---------- brute-force fallback (generic n) ----------
__global__ void surv_partial_bf(const float* __restrict__ theta, const float* __restrict__ T,
                                const float* __restrict__ events, float* __restrict__ bsum, int n) {
    __shared__ float red[BLOCK];
    const int tid = threadIdx.x;
    const int i = blockIdx.x * BLOCK + tid;
    float term = 0.f;
    if (i < n) {
        const float Ti = T[i];
        float risk = 0.f;
        for (int j = 0; j < n; ++j)
            risk += (T[j] >= Ti) ? expf(theta[j]) : 0.f;
        term = (theta[i] - logf(risk)) * events[i];
    }
    red[tid] = term;
    __syncthreads();
    for (int s = BLOCK / 2; s > 0; s >>= 1) {
        if (tid < s) red[tid] += red[tid + s];
        __syncthreads();
    }
    if (tid == 0) bsum[blockIdx.x] = red[0];
}

__global__ void surv_final(const float* __restrict__ bsum, float* __restrict__ out,
                           int nblocks, int n) {
    float v = 0.f;
    for (int b = threadIdx.x; b < nblocks; b += 64) v += bsum[b];
    for (int off = 32; off > 0; off >>= 1) v += __shfl_down(v, off, 64);
    if (threadIdx.x == 0) out[0] = -v / (float)n;
}

extern "C" void kernel_launch(void* const* d_in, const int* in_sizes, int n_in,
                              void* d_out, int out_size, void* d_ws, size_t ws_size,
                              hipStream_t stream) {
    const float* theta  = (const float*)d_in[0];
    const float* T      = (const float*)d_in[1];
    const float* events = (const float*)d_in[2];
    float* out = (float*)d_out;
    const int n = in_sizes[0];                  // 16384

    // fast path: n % 2048 == 0 (512-i groups, 16 splits, 16 waves, float4-even),
    // j-slice fits LDS stage, FBLOCK divides n.
    // ws: partial[NSPLIT][n] f32 | accum | ticket
    const size_t need = (size_t)NSPLIT * n * 4 + 64;
    const bool fast = (n >= 2048) && (n % 2048 == 0) && (n / NSPLIT <= MAXJ)
                      && ((size_t)ws_size >= need);

    if (!fast) {
        const int nbi = (n + BLOCK - 1) / BLOCK;
        float* bsum = (float*)d_ws;
        surv_partial_bf<<<nbi, BLOCK, 0, stream>>>(theta, T, events, bsum, n);
        surv_final<<<1, 64, 0, stream>>>(bsum, out, nbi, n);
        return;
    }

    float* partial = (float*)d_ws;
    float* accum   = partial + (size_t)NSPLIT * n;
    int*   ticket  = (int*)(accum + 1);

    const int ng = n / IPG;                     // 32
    const int mb = ng * NSPLIT;                 // 512 blocks
    const int fb = n / FBLOCK;                  // 64 blocks

    surv_main<<<mb, MT, 0, stream>>>(theta, T, partial, accum, ticket, n);
    surv_fin<<<fb, FBLOCK, 0, stream>>>(theta, events, partial, accum, ticket, out, n);
}